// Round 2
// baseline (836.704 us; speedup 1.0000x reference)
//
#include <hip/hip_runtime.h>
#include <hip/hip_bf16.h>

typedef unsigned short u16;
typedef __attribute__((ext_vector_type(8))) short bf16x8;   // 8 bf16 in 4 VGPRs
typedef __attribute__((ext_vector_type(4))) float f32x4;

#define DEV static __device__ __forceinline__

#define BB 16
#define NN 1024
#define EE 768
#define HH 12
#define DD 64
#define BN (BB*NN)   // 16384

DEV u16 f2bf(float f){ __hip_bfloat16 h = __float2bfloat16(f); u16 u; __builtin_memcpy(&u, &h, 2); return u; }
DEV float bf2f(u16 u){ __hip_bfloat16 h; __builtin_memcpy(&h, &u, 2); return __bfloat162float(h); }
DEV void split2(float v, u16& hi, u16& lo){ hi = f2bf(v); lo = f2bf(v - bf2f(hi)); }
DEV bf16x8 ld8(const u16* p){ return *(const bf16x8*)p; }
DEV f32x4 mfma16(bf16x8 a, bf16x8 b, f32x4 c){ return __builtin_amdgcn_mfma_f32_16x16x32_bf16(a, b, c, 0, 0, 0); }

union U8 { bf16x8 v; u16 e[8]; ushort4 q[2]; };

// ---------------- prep kernels ----------------

__global__ __launch_bounds__(256) void split_x_k(const float* __restrict__ x,
                                                 u16* __restrict__ xh, u16* __restrict__ xl){
  int i = blockIdx.x*256 + threadIdx.x;          // < 3145728
  const float4 v = ((const float4*)x)[i];
  ushort4 h, l;
  split2(v.x, h.x, l.x);
  split2(v.y, h.y, l.y);
  split2(v.z, h.z, l.z);
  split2(v.w, h.w, l.w);
  ((ushort4*)xh)[i] = h;
  ((ushort4*)xl)[i] = l;
}

// W [h][e][d] fp32 -> Wt [h][d][e] bf16 hi(/lo), scale folded (1/8 for Wq)
__global__ __launch_bounds__(256) void pack_w_k(const float* __restrict__ W,
                                                u16* __restrict__ Wh, u16* __restrict__ Wl,
                                                float scale, int dosplit){
  int i = blockIdx.x*256 + threadIdx.x;          // < 589824
  int d = i & 63; int he = i >> 6; int h = he / EE; int e = he - h*EE;
  float v = W[i]*scale;
  u16 hi, lo; split2(v, hi, lo);
  size_t o = (size_t)(h*DD + d)*EE + e;
  Wh[o] = hi;
  if (dosplit) Wl[o] = lo;
}

__global__ __launch_bounds__(256) void pack_wo_k(const float* __restrict__ W, u16* __restrict__ Wt){
  int i = blockIdx.x*256 + threadIdx.x;          // < 49152
  int j = i & 63, k = i >> 6;
  Wt[(size_t)j*EE + k] = f2bf(W[i]);
}

// ---------------- fused QKV projection ----------------
// One block: 128 X-rows x one head; X frags loaded once serve Q(3-pass), K(3-pass), V(1-pass).
// XCD-chunked swizzle, h-fastest inside chunk: X tile stays in XCD L2 across the 12 heads.
__global__ __launch_bounds__(256) void qkv_k(const u16* __restrict__ Xh, const u16* __restrict__ Xl,
                                             const u16* __restrict__ Wqh, const u16* __restrict__ Wql,
                                             const u16* __restrict__ Wkh, const u16* __restrict__ Wkl,
                                             const u16* __restrict__ Wvh,
                                             u16* __restrict__ Qh, u16* __restrict__ Ql,
                                             u16* __restrict__ Kh, u16* __restrict__ Kl,
                                             u16* __restrict__ Vt){
  const int flat = blockIdx.x;                     // 1536 = 8 XCD * 192
  const int swz = (flat & 7)*192 + (flat >> 3);    // bijective XCD chunking
  const int h = swz % 12, rt = swz / 12;           // h fastest within chunk
  const int w = threadIdx.x >> 6, l = threadIdx.x & 63, lr = l & 15, lg = l >> 4;
  const int row0 = rt*128 + w*32;
  const u16* wqh = Wqh + (size_t)h*DD*EE;
  const u16* wql = Wql + (size_t)h*DD*EE;
  const u16* wkh = Wkh + (size_t)h*DD*EE;
  const u16* wkl = Wkl + (size_t)h*DD*EE;
  const u16* wvh = Wvh + (size_t)h*DD*EE;

  f32x4 aq[2][4], ak[2][4], av[2][4];
  #pragma unroll
  for (int m=0;m<2;++m)
    #pragma unroll
    for (int n=0;n<4;++n){ aq[m][n]=f32x4{0.f,0.f,0.f,0.f}; ak[m][n]=f32x4{0.f,0.f,0.f,0.f}; av[m][n]=f32x4{0.f,0.f,0.f,0.f}; }

  for (int kt=0; kt<12; ++kt){
    const int e0 = kt*64;
    bf16x8 ah[2][2], al2[2][2];
    #pragma unroll
    for (int m=0;m<2;++m)
      #pragma unroll
      for (int ks=0;ks<2;++ks){
        size_t o = (size_t)(row0 + m*16 + lr)*EE + e0 + ks*32 + lg*8;
        ah[m][ks]  = ld8(Xh + o);
        al2[m][ks] = ld8(Xl + o);
      }
    #pragma unroll
    for (int ks=0;ks<2;++ks){
      {  // Q 3-pass
        bf16x8 bh[4], bl[4];
        #pragma unroll
        for (int nf=0;nf<4;++nf){
          size_t o = (size_t)(nf*16 + lr)*EE + e0 + ks*32 + lg*8;
          bh[nf] = ld8(wqh + o); bl[nf] = ld8(wql + o);
        }
        #pragma unroll
        for (int m=0;m<2;++m)
          #pragma unroll
          for (int nf=0;nf<4;++nf){
            aq[m][nf] = mfma16(ah[m][ks],  bh[nf], aq[m][nf]);
            aq[m][nf] = mfma16(ah[m][ks],  bl[nf], aq[m][nf]);
            aq[m][nf] = mfma16(al2[m][ks], bh[nf], aq[m][nf]);
          }
      }
      {  // K 3-pass
        bf16x8 bh[4], bl[4];
        #pragma unroll
        for (int nf=0;nf<4;++nf){
          size_t o = (size_t)(nf*16 + lr)*EE + e0 + ks*32 + lg*8;
          bh[nf] = ld8(wkh + o); bl[nf] = ld8(wkl + o);
        }
        #pragma unroll
        for (int m=0;m<2;++m)
          #pragma unroll
          for (int nf=0;nf<4;++nf){
            ak[m][nf] = mfma16(ah[m][ks],  bh[nf], ak[m][nf]);
            ak[m][nf] = mfma16(ah[m][ks],  bl[nf], ak[m][nf]);
            ak[m][nf] = mfma16(al2[m][ks], bh[nf], ak[m][nf]);
          }
      }
      {  // V 1-pass
        bf16x8 bh[4];
        #pragma unroll
        for (int nf=0;nf<4;++nf)
          bh[nf] = ld8(wvh + (size_t)(nf*16 + lr)*EE + e0 + ks*32 + lg*8);
        #pragma unroll
        for (int m=0;m<2;++m)
          #pragma unroll
          for (int nf=0;nf<4;++nf)
            av[m][nf] = mfma16(ah[m][ks], bh[nf], av[m][nf]);
      }
    }
  }

  // stores: Q/K split hi/lo [h][n][d]; V transposed Vt[h][b][d][n]
  const size_t ob = (size_t)h*BN*DD;
  #pragma unroll
  for (int m=0;m<2;++m)
    #pragma unroll
    for (int nf=0;nf<4;++nf){
      #pragma unroll
      for (int j=0;j<4;++j){
        size_t o = ob + (size_t)(row0 + m*16 + lg*4 + j)*DD + nf*16 + lr;
        u16 hi, lo;
        split2(aq[m][nf][j], hi, lo); Qh[o] = hi; Ql[o] = lo;
        split2(ak[m][nf][j], hi, lo); Kh[o] = hi; Kl[o] = lo;
      }
      ushort4 pk;
      pk.x = f2bf(av[m][nf][0]); pk.y = f2bf(av[m][nf][1]);
      pk.z = f2bf(av[m][nf][2]); pk.w = f2bf(av[m][nf][3]);
      int ng = row0 + m*16 + lg*4;
      int b = ng >> 10, n = ng & 1023;
      *(ushort4*)(Vt + ((size_t)((h*16 + b)*DD + nf*16 + lr))*NN + n) = pk;
    }
}

// ---------------- flash attention (swapped operands, zero LDS) ----------------
// S^T = mfma(A=K, B=Q): lane owns q = qf*16 + (l&15); scores s[qf][kf][r] at kv = 16kf+4g+r.
// P fed to PV as B-frag via in-lane packing with k-permutation; V^T A-frag loads use the
// SAME permutation: logical k (g,j) -> kv = 32ks + 16(j>>2) + 4g + (j&3). O^T = mfma(V^T, P).
__global__ __launch_bounds__(256) void flash_k(const u16* __restrict__ Qh, const u16* __restrict__ Ql,
                                               const u16* __restrict__ Kh, const u16* __restrict__ Kl,
                                               const u16* __restrict__ Vt, u16* __restrict__ Cc){
  const int flat = blockIdx.x;
  const int swz = (flat & 7)*192 + (flat >> 3);    // XCD chunking: K/V of a (b,h) stay in one L2
  const int qb = swz & 7, h = (swz >> 3) % 12, b = swz / 96;
  const int l = threadIdx.x & 63, w = threadIdx.x >> 6, lr = l & 15, lg = l >> 4;
  const size_t hb = (size_t)h*BN*DD + (size_t)b*NN*DD;
  const size_t vtb = (size_t)((h*16 + b)*DD);
  const int q0 = qb*128 + w*32;

  // hoist Q B-frags (col = lr -> q, k = lg*8 contiguous along D)
  bf16x8 qfh[2][2], qfl[2][2];
  #pragma unroll
  for (int qf=0;qf<2;++qf)
    #pragma unroll
    for (int ks=0;ks<2;++ks){
      size_t o = hb + (size_t)(q0 + qf*16 + lr)*DD + ks*32 + lg*8;
      qfh[qf][ks] = ld8(Qh + o);
      qfl[qf][ks] = ld8(Ql + o);
    }

  f32x4 acc[2][4];                 // [qf][df] : O^T frags (row=d, col=q)
  float mr[2] = {-1e30f,-1e30f}, ls[2] = {0.f,0.f};
  #pragma unroll
  for (int qf=0;qf<2;++qf)
    #pragma unroll
    for (int df=0;df<4;++df) acc[qf][df] = f32x4{0.f,0.f,0.f,0.f};

  for (int t=0;t<16;++t){
    const int kv0 = t*64;
    f32x4 s[2][4];                 // [qf][kf]
    #pragma unroll
    for (int qf=0;qf<2;++qf)
      #pragma unroll
      for (int kf=0;kf<4;++kf) s[qf][kf] = f32x4{0.f,0.f,0.f,0.f};

    // QK^T (swapped, 3-pass)
    #pragma unroll
    for (int ks=0;ks<2;++ks){
      bf16x8 kh[4], kl2[4];
      #pragma unroll
      for (int kf=0;kf<4;++kf){
        size_t o = hb + (size_t)(kv0 + kf*16 + lr)*DD + ks*32 + lg*8;
        kh[kf]  = ld8(Kh + o);
        kl2[kf] = ld8(Kl + o);
      }
      __builtin_amdgcn_s_setprio(1);
      #pragma unroll
      for (int qf=0;qf<2;++qf)
        #pragma unroll
        for (int kf=0;kf<4;++kf){
          s[qf][kf] = mfma16(kh[kf],  qfh[qf][ks], s[qf][kf]);
          s[qf][kf] = mfma16(kl2[kf], qfh[qf][ks], s[qf][kf]);
          s[qf][kf] = mfma16(kh[kf],  qfl[qf][ks], s[qf][kf]);
        }
      __builtin_amdgcn_s_setprio(0);
    }

    // V^T A-frags with permuted addressing (issue early; hides under softmax VALU)
    bf16x8 va[4][2];
    #pragma unroll
    for (int df=0;df<4;++df)
      #pragma unroll
      for (int ks=0;ks<2;++ks){
        const u16* vp = Vt + (vtb + df*16 + lr)*NN + kv0 + ks*32 + lg*4;
        U8 vu;
        vu.q[0] = *(const ushort4*)(vp);
        vu.q[1] = *(const ushort4*)(vp + 16);
        va[df][ks] = vu.v;
      }

    // in-register online softmax (per lane: 2 q-rows)
    bf16x8 pb[2][2];
    #pragma unroll
    for (int qf=0;qf<2;++qf){
      float pm = -1e30f;
      #pragma unroll
      for (int kf=0;kf<4;++kf)
        #pragma unroll
        for (int r=0;r<4;++r) pm = fmaxf(pm, s[qf][kf][r]);
      pm = fmaxf(pm, __shfl_xor(pm, 16, 64));
      pm = fmaxf(pm, __shfl_xor(pm, 32, 64));
      const float mn = fmaxf(mr[qf], pm);
      const float fs = __expf(mr[qf] - mn);
      mr[qf] = mn;
      float rs = 0.f;
      #pragma unroll
      for (int kf=0;kf<4;++kf)
        #pragma unroll
        for (int r=0;r<4;++r){
          float e = __expf(s[qf][kf][r] - mn);
          s[qf][kf][r] = e;
          rs += e;
        }
      rs += __shfl_xor(rs, 16, 64);
      rs += __shfl_xor(rs, 32, 64);
      ls[qf] = ls[qf]*fs + rs;
      #pragma unroll
      for (int df=0;df<4;++df)
        #pragma unroll
        for (int r=0;r<4;++r) acc[qf][df][r] *= fs;
      // pack P as PV B-frag, k-permuted: elem j <- s[qf][2ks + (j>>2)][j&3]
      #pragma unroll
      for (int ks=0;ks<2;++ks){
        U8 pu;
        #pragma unroll
        for (int j=0;j<8;++j) pu.e[j] = f2bf(s[qf][2*ks + (j>>2)][j&3]);
        pb[qf][ks] = pu.v;
      }
    }

    // PV: O^T += V^T * P
    __builtin_amdgcn_s_setprio(1);
    #pragma unroll
    for (int ks=0;ks<2;++ks)
      #pragma unroll
      for (int qf=0;qf<2;++qf)
        #pragma unroll
        for (int df=0;df<4;++df)
          acc[qf][df] = mfma16(va[df][ks], pb[qf][ks], acc[qf][df]);
    __builtin_amdgcn_s_setprio(0);
  }

  // epilogue: O^T frag: q = qf*16 + lr (lane), d = df*16 + lg*4 + r (regs)
  #pragma unroll
  for (int qf=0;qf<2;++qf){
    const float inv = 1.0f / ls[qf];
    #pragma unroll
    for (int df=0;df<4;++df){
      ushort4 o4;
      o4.x = f2bf(acc[qf][df][0]*inv);
      o4.y = f2bf(acc[qf][df][1]*inv);
      o4.z = f2bf(acc[qf][df][2]*inv);
      o4.w = f2bf(acc[qf][df][3]*inv);
      *(ushort4*)(Cc + (size_t)(b*NN + q0 + qf*16 + lr)*EE + h*DD + df*16 + lg*4) = o4;
    }
  }
}

// ---------------- output projection ----------------
// 64-row tiles -> 256 blocks; wave handles 16 rows.
__global__ __launch_bounds__(256) void gemm_o_k(const u16* __restrict__ Cc, const u16* __restrict__ Wot,
                                                float* __restrict__ out){
  const int rt = blockIdx.x;
  const int w = threadIdx.x >> 6, l = threadIdx.x & 63, lr = l & 15, lg = l >> 4;
  const int row0 = rt*64 + w*16;
  f32x4 acc[4];
  #pragma unroll
  for (int n=0;n<4;++n) acc[n] = f32x4{0.f,0.f,0.f,0.f};

  for (int kt=0; kt<12; ++kt){
    const int e0 = kt*64;
    bf16x8 a[2], bb[4][2];
    #pragma unroll
    for (int ks=0;ks<2;++ks)
      a[ks] = ld8(Cc + (size_t)(row0 + lr)*EE + e0 + ks*32 + lg*8);
    #pragma unroll
    for (int nf=0;nf<4;++nf)
      #pragma unroll
      for (int ks=0;ks<2;++ks)
        bb[nf][ks] = ld8(Wot + (size_t)(nf*16 + lr)*EE + e0 + ks*32 + lg*8);
    #pragma unroll
    for (int ks=0;ks<2;++ks)
      #pragma unroll
      for (int nf=0;nf<4;++nf)
        acc[nf] = mfma16(a[ks], bb[nf][ks], acc[nf]);
  }
  #pragma unroll
  for (int nf=0;nf<4;++nf)
    #pragma unroll
    for (int j=0;j<4;++j)
      out[(size_t)(row0 + lg*4 + j)*DD + nf*16 + lr] = acc[nf][j];
}

// ---------------- launch ----------------
extern "C" void kernel_launch(void* const* d_in, const int* in_sizes, int n_in,
                              void* d_out, int out_size, void* d_ws, size_t ws_size,
                              hipStream_t stream) {
  const float* x  = (const float*)d_in[0];
  const float* Wq = (const float*)d_in[1];
  const float* Wk = (const float*)d_in[2];
  const float* Wv = (const float*)d_in[3];
  const float* Wo = (const float*)d_in[4];
  float* out = (float*)d_out;

  u16* ws = (u16*)d_ws;
  const size_t SB = (size_t)12582912;   // 16384*768 == 12*16384*64
  u16* Xh  = ws;
  u16* Xl  = Xh + SB;
  u16* Qh  = Xl + SB;
  u16* Ql  = Qh + SB;
  u16* Kh  = Ql + SB;
  u16* Kl  = Kh + SB;
  u16* Vt  = Kl + SB;
  u16* Cc  = Vt + SB;
  u16* Wqh = Cc + SB;
  u16* Wql = Wqh + 589824;
  u16* Wkh = Wql + 589824;
  u16* Wkl = Wkh + 589824;
  u16* Wvh = Wkl + 589824;
  u16* Wot = Wvh + 589824;

  split_x_k<<<12288, 256, 0, stream>>>(x, Xh, Xl);
  pack_w_k<<<2304, 256, 0, stream>>>(Wq, Wqh, Wql, 0.125f, 1);   // 1/sqrt(D) folded into Wq
  pack_w_k<<<2304, 256, 0, stream>>>(Wk, Wkh, Wkl, 1.0f, 1);
  pack_w_k<<<2304, 256, 0, stream>>>(Wv, Wvh, Wvh, 1.0f, 0);     // lo unused
  pack_wo_k<<<192, 256, 0, stream>>>(Wo, Wot);

  qkv_k  <<<1536, 256, 0, stream>>>(Xh, Xl, Wqh, Wql, Wkh, Wkl, Wvh, Qh, Ql, Kh, Kl, Vt);
  flash_k<<<1536, 256, 0, stream>>>(Qh, Ql, Kh, Kl, Vt, Cc);
  gemm_o_k<<<256, 256, 0, stream>>>(Cc, Wot, out);
}

// Round 3
// 570.431 us; speedup vs baseline: 1.4668x; 1.4668x over previous
//
#include <hip/hip_runtime.h>
#include <hip/hip_bf16.h>

typedef unsigned short u16;
typedef __attribute__((ext_vector_type(8))) short bf16x8;   // 8 bf16 in 4 VGPRs
typedef __attribute__((ext_vector_type(4))) float f32x4;

#define DEV static __device__ __forceinline__

#define BB 16
#define NN 1024
#define EE 768
#define HH 12
#define DD 64
#define BN (BB*NN)   // 16384

DEV u16 f2bf(float f){ __hip_bfloat16 h = __float2bfloat16(f); u16 u; __builtin_memcpy(&u, &h, 2); return u; }
DEV float bf2f(u16 u){ __hip_bfloat16 h; __builtin_memcpy(&h, &u, 2); return __bfloat162float(h); }
DEV void split2(float v, u16& hi, u16& lo){ hi = f2bf(v); lo = f2bf(v - bf2f(hi)); }
DEV bf16x8 ld8(const u16* p){ return *(const bf16x8*)p; }
DEV f32x4 mfma16(bf16x8 a, bf16x8 b, f32x4 c){ return __builtin_amdgcn_mfma_f32_16x16x32_bf16(a, b, c, 0, 0, 0); }

union U8 { bf16x8 v; u16 e[8]; ushort4 q[2]; };

// async global->LDS, 16B per lane. LDS dst must be wave-uniform; HW adds lane*16.
DEV void stage16(const u16* g, u16* l){
  __builtin_amdgcn_global_load_lds((const __attribute__((address_space(1))) void*)g,
                                   (__attribute__((address_space(3))) void*)l,
                                   16, 0, 0);
}

// ---------------- prep kernels ----------------

__global__ __launch_bounds__(256) void split_x_k(const float* __restrict__ x,
                                                 u16* __restrict__ xh, u16* __restrict__ xl){
  int i = blockIdx.x*256 + threadIdx.x;          // < 3145728
  const float4 v = ((const float4*)x)[i];
  ushort4 h, l;
  split2(v.x, h.x, l.x);
  split2(v.y, h.y, l.y);
  split2(v.z, h.z, l.z);
  split2(v.w, h.w, l.w);
  ((ushort4*)xh)[i] = h;
  ((ushort4*)xl)[i] = l;
}

// BT1[1536][2304]: col c -> head h=c>>7, group g=(c>>6)&1 (0=Q,1=K), d=c&63.
// k: seg 0 = W_hi, seg 1 = W_lo, seg 2 = W_hi  (pairs with A_ext = [Xh|Xh|Xl]).
__global__ __launch_bounds__(256) void pack_bt1_k(const float* __restrict__ Wq,
                                                  const float* __restrict__ Wk,
                                                  u16* __restrict__ BT1){
  int i = blockIdx.x*256 + threadIdx.x;          // < 3538944
  int c = i / 2304, k = i - c*2304;
  int seg = (k >= 768) + (k >= 1536);
  int e = k - seg*768;
  int h = c >> 7, g = (c >> 6) & 1, d = c & 63;
  const float* W = g ? Wk : Wq;
  float v = W[((size_t)h*EE + e)*DD + d] * (g ? 1.0f : 0.125f);
  u16 hi, lo; split2(v, hi, lo);
  BT1[i] = (seg == 1) ? lo : hi;
}

// BT2[768][768]: col c -> h=c>>6, d=c&63; k=e. Plain bf16.
__global__ __launch_bounds__(256) void pack_bt2_k(const float* __restrict__ Wv,
                                                  u16* __restrict__ BT2){
  int i = blockIdx.x*256 + threadIdx.x;          // < 589824
  int c = i / 768, e = i - c*768;
  int h = c >> 6, d = c & 63;
  BT2[i] = f2bf(Wv[((size_t)h*EE + e)*DD + d]);
}

__global__ __launch_bounds__(256) void pack_wo_k(const float* __restrict__ W, u16* __restrict__ Wt){
  int i = blockIdx.x*256 + threadIdx.x;          // < 49152
  int j = i & 63, k = i >> 6;
  Wt[(size_t)j*EE + k] = f2bf(W[i]);
}

// ---------------- big staged GEMM (m97-style 2-phase, 128x128 tile, BK=64) ----------------
// A_ext[16384][KT*64]: MODE0: kt<24 -> Xh slice (kt%12), kt>=24 -> Xl slice. MODE1: Xh.
// BT[cols][KT*64] row-major (B transposed). 4 waves 2x2, wave tile 64x64, acc 4x4.
// MODE0: epilogue splits C into (Qh,Ql) [wc=0] / (Kh,Kl) [wc=1], head = blk-col.
// MODE1: epilogue packs bf16 into Vt[h*16+b][d][n] (n-contiguous ushort4).
template<int KT, int MODE>
__global__ __launch_bounds__(256) void gemm_big_k(const u16* __restrict__ Xh, const u16* __restrict__ Xl,
                                                  const u16* __restrict__ BT,
                                                  u16* __restrict__ O0h, u16* __restrict__ O0l,
                                                  u16* __restrict__ O1h, u16* __restrict__ O1l){
  __shared__ u16 lds[2][2][8192];                // [buf][A/B][128*64] = 64 KB
  constexpr int NB  = (MODE == 0) ? 12 : 6;      // col-tiles
  constexpr int CPX = (MODE == 0) ? 192 : 96;    // blocks per XCD chunk
  constexpr int KE  = KT*64;                     // B K-extent (elems)

  const int flat = blockIdx.x;
  const int swz = (flat & 7)*CPX + (flat >> 3);  // XCD-chunked, bc fastest (A-panel L2 reuse)
  const int rt = swz / NB, bc = swz - rt*NB;
  const int row0 = rt*128, col0 = bc*128;
  const int tid = threadIdx.x;
  const int w = tid >> 6, l = tid & 63, lr = l & 15, lg = l >> 4;
  const int wr = w >> 1, wc = w & 1;
  const int sr = l >> 3, sce = (l & 7)*8;        // staging: row-in-8, col elem

  f32x4 acc[4][4];
  #pragma unroll
  for (int m=0;m<4;++m)
    #pragma unroll
    for (int n=0;n<4;++n) acc[m][n] = f32x4{0.f,0.f,0.f,0.f};

  auto stage = [&](int buf, int kt){
    const u16* asrc = (MODE == 0 && kt >= 24) ? Xl : Xh;
    const int e0 = (MODE == 0) ? (kt - (kt >= 24 ? 24 : (kt >= 12 ? 12 : 0)))*64 : kt*64;
    const u16* ab = asrc + (size_t)row0*EE + e0 + sce;
    const u16* bb = BT + (size_t)col0*KE + kt*64 + sce;
    u16* la = &lds[buf][0][0];
    u16* lb = &lds[buf][1][0];
    #pragma unroll
    for (int j=0;j<4;++j){
      const int it = j*4 + w;                    // 16 sub-blocks of 8 rows
      stage16(ab + (size_t)(it*8 + sr)*EE, la + it*512);
      stage16(bb + (size_t)(it*8 + sr)*KE, lb + it*512);
    }
  };

  stage(0, 0);
  __syncthreads();

  for (int kt=0; kt<KT; ++kt){
    const int buf = kt & 1;
    if (kt + 1 < KT) stage(buf ^ 1, kt + 1);

    const u16* la = &lds[buf][0][0];
    const u16* lb = &lds[buf][1][0];
    bf16x8 af[4][2], bfr[4][2];
    #pragma unroll
    for (int m=0;m<4;++m)
      #pragma unroll
      for (int ks=0;ks<2;++ks)
        af[m][ks] = ld8(la + (wr*64 + m*16 + lr)*64 + ks*32 + lg*8);
    #pragma unroll
    for (int n=0;n<4;++n)
      #pragma unroll
      for (int ks=0;ks<2;++ks)
        bfr[n][ks] = ld8(lb + (wc*64 + n*16 + lr)*64 + ks*32 + lg*8);

    #pragma unroll
    for (int ks=0;ks<2;++ks)
      #pragma unroll
      for (int m=0;m<4;++m)
        #pragma unroll
        for (int n=0;n<4;++n)
          acc[m][n] = mfma16(af[m][ks], bfr[n][ks], acc[m][n]);

    __syncthreads();   // drains vmcnt (stage done) + all waves done reading buf
  }

  if constexpr (MODE == 0){
    u16* Dh = wc ? O1h : O0h;
    u16* Dl = wc ? O1l : O0l;
    const size_t base = (size_t)bc*BN*DD;        // head = bc
    #pragma unroll
    for (int m=0;m<4;++m)
      #pragma unroll
      for (int n=0;n<4;++n)
        #pragma unroll
        for (int j=0;j<4;++j){
          int r = row0 + wr*64 + m*16 + lg*4 + j;
          int d = n*16 + lr;
          size_t o = base + (size_t)r*DD + d;
          u16 hi, lo; split2(acc[m][n][j], hi, lo);
          Dh[o] = hi; Dl[o] = lo;
        }
  } else {
    #pragma unroll
    for (int m=0;m<4;++m)
      #pragma unroll
      for (int n=0;n<4;++n){
        int c = col0 + wc*64 + n*16 + lr;
        int hh = c >> 6, d = c & 63;
        int r = row0 + wr*64 + m*16 + lg*4;
        int b = r >> 10, nn = r & 1023;
        ushort4 pk;
        pk.x = f2bf(acc[m][n][0]); pk.y = f2bf(acc[m][n][1]);
        pk.z = f2bf(acc[m][n][2]); pk.w = f2bf(acc[m][n][3]);
        *(ushort4*)(O0h + ((size_t)((hh*16 + b)*DD + d))*NN + nn) = pk;
      }
  }
}

// ---------------- flash attention (swapped operands, zero LDS) ----------------
__global__ __launch_bounds__(256) void flash_k(const u16* __restrict__ Qh, const u16* __restrict__ Ql,
                                               const u16* __restrict__ Kh, const u16* __restrict__ Kl,
                                               const u16* __restrict__ Vt, u16* __restrict__ Cc){
  const int flat = blockIdx.x;
  const int swz = (flat & 7)*192 + (flat >> 3);    // XCD chunking: K/V of a (b,h) stay in one L2
  const int qb = swz & 7, h = (swz >> 3) % 12, b = swz / 96;
  const int l = threadIdx.x & 63, w = threadIdx.x >> 6, lr = l & 15, lg = l >> 4;
  const size_t hb = (size_t)h*BN*DD + (size_t)b*NN*DD;
  const size_t vtb = (size_t)((h*16 + b)*DD);
  const int q0 = qb*128 + w*32;

  bf16x8 qfh[2][2], qfl[2][2];
  #pragma unroll
  for (int qf=0;qf<2;++qf)
    #pragma unroll
    for (int ks=0;ks<2;++ks){
      size_t o = hb + (size_t)(q0 + qf*16 + lr)*DD + ks*32 + lg*8;
      qfh[qf][ks] = ld8(Qh + o);
      qfl[qf][ks] = ld8(Ql + o);
    }

  f32x4 acc[2][4];                 // [qf][df] : O^T frags (row=d, col=q)
  float mr[2] = {-1e30f,-1e30f}, ls[2] = {0.f,0.f};
  #pragma unroll
  for (int qf=0;qf<2;++qf)
    #pragma unroll
    for (int df=0;df<4;++df) acc[qf][df] = f32x4{0.f,0.f,0.f,0.f};

  for (int t=0;t<16;++t){
    const int kv0 = t*64;
    f32x4 s[2][4];                 // [qf][kf]
    #pragma unroll
    for (int qf=0;qf<2;++qf)
      #pragma unroll
      for (int kf=0;kf<4;++kf) s[qf][kf] = f32x4{0.f,0.f,0.f,0.f};

    #pragma unroll
    for (int ks=0;ks<2;++ks){
      bf16x8 kh[4], kl2[4];
      #pragma unroll
      for (int kf=0;kf<4;++kf){
        size_t o = hb + (size_t)(kv0 + kf*16 + lr)*DD + ks*32 + lg*8;
        kh[kf]  = ld8(Kh + o);
        kl2[kf] = ld8(Kl + o);
      }
      __builtin_amdgcn_s_setprio(1);
      #pragma unroll
      for (int qf=0;qf<2;++qf)
        #pragma unroll
        for (int kf=0;kf<4;++kf){
          s[qf][kf] = mfma16(kh[kf],  qfh[qf][ks], s[qf][kf]);
          s[qf][kf] = mfma16(kl2[kf], qfh[qf][ks], s[qf][kf]);
          s[qf][kf] = mfma16(kh[kf],  qfl[qf][ks], s[qf][kf]);
        }
      __builtin_amdgcn_s_setprio(0);
    }

    // V^T A-frags with permuted addressing (issue early; hides under softmax VALU)
    bf16x8 va[4][2];
    #pragma unroll
    for (int df=0;df<4;++df)
      #pragma unroll
      for (int ks=0;ks<2;++ks){
        const u16* vp = Vt + (vtb + df*16 + lr)*NN + kv0 + ks*32 + lg*4;
        U8 vu;
        vu.q[0] = *(const ushort4*)(vp);
        vu.q[1] = *(const ushort4*)(vp + 16);
        va[df][ks] = vu.v;
      }

    // in-register online softmax (per lane: 2 q-rows)
    bf16x8 pb[2][2];
    #pragma unroll
    for (int qf=0;qf<2;++qf){
      float pm = -1e30f;
      #pragma unroll
      for (int kf=0;kf<4;++kf)
        #pragma unroll
        for (int r=0;r<4;++r) pm = fmaxf(pm, s[qf][kf][r]);
      pm = fmaxf(pm, __shfl_xor(pm, 16, 64));
      pm = fmaxf(pm, __shfl_xor(pm, 32, 64));
      const float mn = fmaxf(mr[qf], pm);
      const float fs = __expf(mr[qf] - mn);
      mr[qf] = mn;
      float rs = 0.f;
      #pragma unroll
      for (int kf=0;kf<4;++kf)
        #pragma unroll
        for (int r=0;r<4;++r){
          float e = __expf(s[qf][kf][r] - mn);
          s[qf][kf][r] = e;
          rs += e;
        }
      rs += __shfl_xor(rs, 16, 64);
      rs += __shfl_xor(rs, 32, 64);
      ls[qf] = ls[qf]*fs + rs;
      #pragma unroll
      for (int df=0;df<4;++df)
        #pragma unroll
        for (int r=0;r<4;++r) acc[qf][df][r] *= fs;
      #pragma unroll
      for (int ks=0;ks<2;++ks){
        U8 pu;
        #pragma unroll
        for (int j=0;j<8;++j) pu.e[j] = f2bf(s[qf][2*ks + (j>>2)][j&3]);
        pb[qf][ks] = pu.v;
      }
    }

    __builtin_amdgcn_s_setprio(1);
    #pragma unroll
    for (int ks=0;ks<2;++ks)
      #pragma unroll
      for (int qf=0;qf<2;++qf)
        #pragma unroll
        for (int df=0;df<4;++df)
          acc[qf][df] = mfma16(va[df][ks], pb[qf][ks], acc[qf][df]);
    __builtin_amdgcn_s_setprio(0);
  }

  #pragma unroll
  for (int qf=0;qf<2;++qf){
    const float inv = 1.0f / ls[qf];
    #pragma unroll
    for (int df=0;df<4;++df){
      ushort4 o4;
      o4.x = f2bf(acc[qf][df][0]*inv);
      o4.y = f2bf(acc[qf][df][1]*inv);
      o4.z = f2bf(acc[qf][df][2]*inv);
      o4.w = f2bf(acc[qf][df][3]*inv);
      *(ushort4*)(Cc + (size_t)(b*NN + q0 + qf*16 + lr)*EE + h*DD + df*16 + lg*4) = o4;
    }
  }
}

// ---------------- output projection ----------------
__global__ __launch_bounds__(256) void gemm_o_k(const u16* __restrict__ Cc, const u16* __restrict__ Wot,
                                                float* __restrict__ out){
  const int rt = blockIdx.x;
  const int w = threadIdx.x >> 6, l = threadIdx.x & 63, lr = l & 15, lg = l >> 4;
  const int row0 = rt*64 + w*16;
  f32x4 acc[4];
  #pragma unroll
  for (int n=0;n<4;++n) acc[n] = f32x4{0.f,0.f,0.f,0.f};

  for (int kt=0; kt<12; ++kt){
    const int e0 = kt*64;
    bf16x8 a[2], bb[4][2];
    #pragma unroll
    for (int ks=0;ks<2;++ks)
      a[ks] = ld8(Cc + (size_t)(row0 + lr)*EE + e0 + ks*32 + lg*8);
    #pragma unroll
    for (int nf=0;nf<4;++nf)
      #pragma unroll
      for (int ks=0;ks<2;++ks)
        bb[nf][ks] = ld8(Wot + (size_t)(nf*16 + lr)*EE + e0 + ks*32 + lg*8);
    #pragma unroll
    for (int ks=0;ks<2;++ks)
      #pragma unroll
      for (int nf=0;nf<4;++nf)
        acc[nf] = mfma16(a[ks], bb[nf][ks], acc[nf]);
  }
  #pragma unroll
  for (int nf=0;nf<4;++nf)
    #pragma unroll
    for (int j=0;j<4;++j)
      out[(size_t)(row0 + lg*4 + j)*DD + nf*16 + lr] = acc[nf][j];
}

// ---------------- launch ----------------
extern "C" void kernel_launch(void* const* d_in, const int* in_sizes, int n_in,
                              void* d_out, int out_size, void* d_ws, size_t ws_size,
                              hipStream_t stream) {
  const float* x  = (const float*)d_in[0];
  const float* Wq = (const float*)d_in[1];
  const float* Wk = (const float*)d_in[2];
  const float* Wv = (const float*)d_in[3];
  const float* Wo = (const float*)d_in[4];
  float* out = (float*)d_out;

  u16* ws = (u16*)d_ws;
  const size_t SB = (size_t)12582912;   // 16384*768
  u16* Xh  = ws;
  u16* Xl  = Xh + SB;
  u16* Qh  = Xl + SB;
  u16* Ql  = Qh + SB;
  u16* Kh  = Ql + SB;
  u16* Kl  = Kh + SB;
  u16* Vt  = Kl + SB;
  u16* Cc  = Vt + SB;
  u16* Wot = Cc + SB;
  // BT1/BT2 alias into Cc: written by packs, read by GEMMs, then Cc is fully
  // overwritten by flash_k before gemm_o_k reads it (in-stream ordering).
  u16* BT1 = Cc;                        // 1536*2304 = 3538944 elems
  u16* BT2 = Cc + 3538944;              // 768*768   =  589824 elems

  split_x_k <<<12288, 256, 0, stream>>>(x, Xh, Xl);
  pack_bt1_k<<<13824, 256, 0, stream>>>(Wq, Wk, BT1);
  pack_bt2_k<<<2304,  256, 0, stream>>>(Wv, BT2);
  pack_wo_k <<<192,   256, 0, stream>>>(Wo, Wot);

  gemm_big_k<36,0><<<1536, 256, 0, stream>>>(Xh, Xl, BT1, Qh, Ql, Kh, Kl);
  gemm_big_k<12,1><<<768,  256, 0, stream>>>(Xh, Xl, BT2, Vt, nullptr, nullptr, nullptr);
  flash_k   <<<1536, 256, 0, stream>>>(Qh, Ql, Kh, Kl, Vt, Cc);
  gemm_o_k  <<<256,  256, 0, stream>>>(Cc, Wot, out);
}

// Round 4
// 435.943 us; speedup vs baseline: 1.9193x; 1.3085x over previous
//
#include <hip/hip_runtime.h>
#include <hip/hip_bf16.h>

typedef unsigned short u16;
typedef __attribute__((ext_vector_type(8))) short bf16x8;   // 8 bf16 in 4 VGPRs
typedef __attribute__((ext_vector_type(4))) float f32x4;

#define DEV static __device__ __forceinline__

#define BB 16
#define NN 1024
#define EE 768
#define HH 12
#define DD 64
#define BN (BB*NN)   // 16384

DEV u16 f2bf(float f){ __hip_bfloat16 h = __float2bfloat16(f); u16 u; __builtin_memcpy(&u, &h, 2); return u; }
DEV float bf2f(u16 u){ __hip_bfloat16 h; __builtin_memcpy(&h, &u, 2); return __bfloat162float(h); }
DEV void split2(float v, u16& hi, u16& lo){ hi = f2bf(v); lo = f2bf(v - bf2f(hi)); }
DEV bf16x8 ld8(const u16* p){ return *(const bf16x8*)p; }
DEV f32x4 mfma16(bf16x8 a, bf16x8 b, f32x4 c){ return __builtin_amdgcn_mfma_f32_16x16x32_bf16(a, b, c, 0, 0, 0); }

union U8 { bf16x8 v; u16 e[8]; ushort4 q[2]; };

// async global->LDS, 16B per lane. LDS dst must be wave-uniform; HW adds lane*16.
DEV void stage16(const u16* g, u16* l){
  __builtin_amdgcn_global_load_lds((const __attribute__((address_space(1))) void*)g,
                                   (__attribute__((address_space(3))) void*)l,
                                   16, 0, 0);
}

// ---------------- prep kernels ----------------

__global__ __launch_bounds__(256) void split_x_k(const float* __restrict__ x,
                                                 u16* __restrict__ xh, u16* __restrict__ xl){
  int i = blockIdx.x*256 + threadIdx.x;          // < 3145728
  const float4 v = ((const float4*)x)[i];
  ushort4 h, l;
  split2(v.x, h.x, l.x);
  split2(v.y, h.y, l.y);
  split2(v.z, h.z, l.z);
  split2(v.w, h.w, l.w);
  ((ushort4*)xh)[i] = h;
  ((ushort4*)xl)[i] = l;
}

// BT1[1536][2304]: col c -> head h=c>>7, group g=(c>>6)&1 (0=Q,1=K), d=c&63.
// k: seg 0 = W_hi, seg 1 = W_lo, seg 2 = W_hi  (pairs with A_ext = [Xh|Xh|Xl]).
// Q scale folds 1/sqrt(D) AND log2(e): flash softmax runs in exp2 domain.
__global__ __launch_bounds__(256) void pack_bt1_k(const float* __restrict__ Wq,
                                                  const float* __restrict__ Wk,
                                                  u16* __restrict__ BT1){
  int i = blockIdx.x*256 + threadIdx.x;          // < 3538944
  int c = i / 2304, k = i - c*2304;
  int seg = (k >= 768) + (k >= 1536);
  int e = k - seg*768;
  int h = c >> 7, g = (c >> 6) & 1, d = c & 63;
  const float* W = g ? Wk : Wq;
  float v = W[((size_t)h*EE + e)*DD + d] * (g ? 1.0f : 0.125f*1.4426950408889634f);
  u16 hi, lo; split2(v, hi, lo);
  BT1[i] = (seg == 1) ? lo : hi;
}

// BT2[768][768]: col c -> h=c>>6, d=c&63; k=e. Plain bf16.
__global__ __launch_bounds__(256) void pack_bt2_k(const float* __restrict__ Wv,
                                                  u16* __restrict__ BT2){
  int i = blockIdx.x*256 + threadIdx.x;          // < 589824
  int c = i / 768, e = i - c*768;
  int h = c >> 6, d = c & 63;
  BT2[i] = f2bf(Wv[((size_t)h*EE + e)*DD + d]);
}

__global__ __launch_bounds__(256) void pack_wo_k(const float* __restrict__ W, u16* __restrict__ Wt){
  int i = blockIdx.x*256 + threadIdx.x;          // < 49152
  int j = i & 63, k = i >> 6;
  Wt[(size_t)j*EE + k] = f2bf(W[i]);
}

// ---------------- big staged GEMM (m97-style 2-phase, 128x128 tile, BK=64) ----------------
template<int KT, int MODE>
__global__ __launch_bounds__(256) void gemm_big_k(const u16* __restrict__ Xh, const u16* __restrict__ Xl,
                                                  const u16* __restrict__ BT,
                                                  u16* __restrict__ O0h, u16* __restrict__ O0l,
                                                  u16* __restrict__ O1h, u16* __restrict__ O1l){
  __shared__ u16 lds[2][2][8192];                // [buf][A/B][128*64] = 64 KB
  constexpr int NB  = (MODE == 0) ? 12 : 6;      // col-tiles
  constexpr int CPX = (MODE == 0) ? 192 : 96;    // blocks per XCD chunk
  constexpr int KE  = KT*64;                     // B K-extent (elems)

  const int flat = blockIdx.x;
  const int swz = (flat & 7)*CPX + (flat >> 3);  // XCD-chunked, bc fastest (A-panel L2 reuse)
  const int rt = swz / NB, bc = swz - rt*NB;
  const int row0 = rt*128, col0 = bc*128;
  const int tid = threadIdx.x;
  const int w = tid >> 6, l = tid & 63, lr = l & 15, lg = l >> 4;
  const int wr = w >> 1, wc = w & 1;
  const int sr = l >> 3, sce = (l & 7)*8;        // staging: row-in-8, col elem

  f32x4 acc[4][4];
  #pragma unroll
  for (int m=0;m<4;++m)
    #pragma unroll
    for (int n=0;n<4;++n) acc[m][n] = f32x4{0.f,0.f,0.f,0.f};

  auto stage = [&](int buf, int kt){
    const u16* asrc = (MODE == 0 && kt >= 24) ? Xl : Xh;
    const int e0 = (MODE == 0) ? (kt - (kt >= 24 ? 24 : (kt >= 12 ? 12 : 0)))*64 : kt*64;
    const u16* ab = asrc + (size_t)row0*EE + e0 + sce;
    const u16* bb = BT + (size_t)col0*KE + kt*64 + sce;
    u16* la = &lds[buf][0][0];
    u16* lb = &lds[buf][1][0];
    #pragma unroll
    for (int j=0;j<4;++j){
      const int it = j*4 + w;                    // 16 sub-blocks of 8 rows
      stage16(ab + (size_t)(it*8 + sr)*EE, la + it*512);
      stage16(bb + (size_t)(it*8 + sr)*KE, lb + it*512);
    }
  };

  stage(0, 0);
  __syncthreads();

  for (int kt=0; kt<KT; ++kt){
    const int buf = kt & 1;
    if (kt + 1 < KT) stage(buf ^ 1, kt + 1);

    const u16* la = &lds[buf][0][0];
    const u16* lb = &lds[buf][1][0];
    bf16x8 af[4][2], bfr[4][2];
    #pragma unroll
    for (int m=0;m<4;++m)
      #pragma unroll
      for (int ks=0;ks<2;++ks)
        af[m][ks] = ld8(la + (wr*64 + m*16 + lr)*64 + ks*32 + lg*8);
    #pragma unroll
    for (int n=0;n<4;++n)
      #pragma unroll
      for (int ks=0;ks<2;++ks)
        bfr[n][ks] = ld8(lb + (wc*64 + n*16 + lr)*64 + ks*32 + lg*8);

    #pragma unroll
    for (int ks=0;ks<2;++ks)
      #pragma unroll
      for (int m=0;m<4;++m)
        #pragma unroll
        for (int n=0;n<4;++n)
          acc[m][n] = mfma16(af[m][ks], bfr[n][ks], acc[m][n]);

    __syncthreads();   // drains vmcnt (stage done) + all waves done reading buf
  }

  if constexpr (MODE == 0){
    u16* Dh = wc ? O1h : O0h;
    u16* Dl = wc ? O1l : O0l;
    const size_t base = (size_t)bc*BN*DD;        // head = bc
    #pragma unroll
    for (int m=0;m<4;++m)
      #pragma unroll
      for (int n=0;n<4;++n)
        #pragma unroll
        for (int j=0;j<4;++j){
          int r = row0 + wr*64 + m*16 + lg*4 + j;
          int d = n*16 + lr;
          size_t o = base + (size_t)r*DD + d;
          u16 hi, lo; split2(acc[m][n][j], hi, lo);
          Dh[o] = hi; Dl[o] = lo;
        }
  } else {
    #pragma unroll
    for (int m=0;m<4;++m)
      #pragma unroll
      for (int n=0;n<4;++n){
        int c = col0 + wc*64 + n*16 + lr;
        int hh = c >> 6, d = c & 63;
        int r = row0 + wr*64 + m*16 + lg*4;
        int b = r >> 10, nn = r & 1023;
        ushort4 pk;
        pk.x = f2bf(acc[m][n][0]); pk.y = f2bf(acc[m][n][1]);
        pk.z = f2bf(acc[m][n][2]); pk.w = f2bf(acc[m][n][3]);
        *(ushort4*)(O0h + ((size_t)((hh*16 + b)*DD + d))*NN + nn) = pk;
      }
  }
}

// ---------------- flash attention v3: swapped operands + LDS-staged K (dbuf) ----------------
// K hi/lo tiles staged via global_load_lds with pre-swizzled SOURCE addresses; reads use the
// matching XOR swizzle (byte ^= (row&7)<<4) -> 2-way banks (free). Softmax in exp2 domain
// (log2e folded into Wq). Exact defer-max: skip rescale when no new max (fs would be 1).
__global__ __launch_bounds__(256) void flash_k(const u16* __restrict__ Qh, const u16* __restrict__ Ql,
                                               const u16* __restrict__ Kh, const u16* __restrict__ Kl,
                                               const u16* __restrict__ Vt, u16* __restrict__ Cc){
  __shared__ u16 kbuf[2][2][4096];                 // [buf][hi/lo][64*64] = 32 KB
  const int flat = blockIdx.x;
  const int swz = (flat & 7)*192 + (flat >> 3);    // XCD chunking: K/V of a (b,h) stay in one L2
  const int qb = swz & 7, h = (swz >> 3) % 12, b = swz / 96;
  const int l = threadIdx.x & 63, w = threadIdx.x >> 6, lr = l & 15, lg = l >> 4;
  const size_t hb = (size_t)h*BN*DD + (size_t)b*NN*DD;
  const size_t vtb = (size_t)((h*16 + b)*DD);
  const int q0 = qb*128 + w*32;

  // staging geometry: chunk = 8 rows x 128B; lane l covers row (l>>3), swizzled col 8*((l&7)^(l>>3))
  const int srow = l >> 3;
  const int scol = 8*((l & 7) ^ srow);

  auto stage = [&](int buf, int t){
    const int kv0 = t*64;
    #pragma unroll
    for (int j=0;j<4;++j){
      const int c = w*4 + j;                       // 0..15: 0-7 Kh, 8-15 Kl
      const u16* src = (c < 8) ? Kh : Kl;
      const int cr = (c & 7)*8;
      stage16(src + hb + (size_t)(kv0 + cr + srow)*DD + scol,
              &kbuf[buf][c >> 3][(c & 7)*512]);
    }
  };

  // hoist Q B-frags (col = lr -> q, k = lg*8 contiguous along D)
  bf16x8 qfh[2][2], qfl[2][2];
  #pragma unroll
  for (int qf=0;qf<2;++qf)
    #pragma unroll
    for (int ks=0;ks<2;++ks){
      size_t o = hb + (size_t)(q0 + qf*16 + lr)*DD + ks*32 + lg*8;
      qfh[qf][ks] = ld8(Qh + o);
      qfl[qf][ks] = ld8(Ql + o);
    }

  f32x4 acc[2][4];                 // [qf][df] : O^T frags (row=d, col=q)
  float mr[2] = {-1e30f,-1e30f}, ls[2] = {0.f,0.f};
  #pragma unroll
  for (int qf=0;qf<2;++qf)
    #pragma unroll
    for (int df=0;df<4;++df) acc[qf][df] = f32x4{0.f,0.f,0.f,0.f};

  stage(0, 0);
  __syncthreads();

  for (int t=0;t<16;++t){
    const int buf = t & 1;
    const int kv0 = t*64;

    // V^T A-frags first (oldest vmem ops -> waiting for them leaves stage in flight)
    bf16x8 va[4][2];
    #pragma unroll
    for (int df=0;df<4;++df)
      #pragma unroll
      for (int ks=0;ks<2;++ks){
        const u16* vp = Vt + (vtb + df*16 + lr)*NN + kv0 + ks*32 + lg*4;
        U8 vu;
        vu.q[0] = *(const ushort4*)(vp);
        vu.q[1] = *(const ushort4*)(vp + 16);
        va[df][ks] = vu.v;
      }

    if (t + 1 < 16) stage(buf ^ 1, t + 1);         // prefetch next K tile (hides under softmax+PV)

    // QK^T from LDS (swapped, 3-pass), per-ks frag window
    f32x4 s[2][4];                 // [qf][kf]
    #pragma unroll
    for (int qf=0;qf<2;++qf)
      #pragma unroll
      for (int kf=0;kf<4;++kf) s[qf][kf] = f32x4{0.f,0.f,0.f,0.f};

    const char* kb = (const char*)&kbuf[buf][0][0];
    #pragma unroll
    for (int ks=0;ks<2;++ks){
      bf16x8 kh[4], kl2[4];
      #pragma unroll
      for (int kf=0;kf<4;++kf){
        const int r = kf*16 + lr;
        const int sw = (ks*64 + lg*16) ^ ((lr & 7) << 4);
        kh[kf]  = *(const bf16x8*)(kb + r*128 + sw);
        kl2[kf] = *(const bf16x8*)(kb + 8192 + r*128 + sw);
      }
      __builtin_amdgcn_s_setprio(1);
      #pragma unroll
      for (int qf=0;qf<2;++qf)
        #pragma unroll
        for (int kf=0;kf<4;++kf){
          s[qf][kf] = mfma16(kh[kf],  qfh[qf][ks], s[qf][kf]);
          s[qf][kf] = mfma16(kl2[kf], qfh[qf][ks], s[qf][kf]);
          s[qf][kf] = mfma16(kh[kf],  qfl[qf][ks], s[qf][kf]);
        }
      __builtin_amdgcn_s_setprio(0);
    }

    // in-register online softmax (exp2 domain; per lane: 2 q-rows)
    bf16x8 pb[2][2];
    #pragma unroll
    for (int qf=0;qf<2;++qf){
      float pm = -1e30f;
      #pragma unroll
      for (int kf=0;kf<4;++kf)
        #pragma unroll
        for (int r=0;r<4;++r) pm = fmaxf(pm, s[qf][kf][r]);
      pm = fmaxf(pm, __shfl_xor(pm, 16, 64));
      pm = fmaxf(pm, __shfl_xor(pm, 32, 64));
      if (!__all(pm <= mr[qf])){                   // exact skip: otherwise fs==1
        const float mn = fmaxf(mr[qf], pm);
        const float fs = exp2f(mr[qf] - mn);
        mr[qf] = mn;
        ls[qf] *= fs;
        #pragma unroll
        for (int df=0;df<4;++df)
          #pragma unroll
          for (int r=0;r<4;++r) acc[qf][df][r] *= fs;
      }
      float rs = 0.f;
      #pragma unroll
      for (int kf=0;kf<4;++kf)
        #pragma unroll
        for (int r=0;r<4;++r){
          float e = exp2f(s[qf][kf][r] - mr[qf]);
          s[qf][kf][r] = e;
          rs += e;
        }
      rs += __shfl_xor(rs, 16, 64);
      rs += __shfl_xor(rs, 32, 64);
      ls[qf] += rs;
      // pack P as PV B-frag, k-permuted: elem j <- s[qf][2ks + (j>>2)][j&3]
      #pragma unroll
      for (int ks=0;ks<2;++ks){
        U8 pu;
        #pragma unroll
        for (int j=0;j<8;++j) pu.e[j] = f2bf(s[qf][2*ks + (j>>2)][j&3]);
        pb[qf][ks] = pu.v;
      }
    }

    // PV: O^T += V^T * P
    __builtin_amdgcn_s_setprio(1);
    #pragma unroll
    for (int ks=0;ks<2;++ks)
      #pragma unroll
      for (int qf=0;qf<2;++qf)
        #pragma unroll
        for (int df=0;df<4;++df)
          acc[qf][df] = mfma16(va[df][ks], pb[qf][ks], acc[qf][df]);
    __builtin_amdgcn_s_setprio(0);

    __syncthreads();               // stage(t+1) drained; all waves done with kbuf[buf]
  }

  #pragma unroll
  for (int qf=0;qf<2;++qf){
    const float inv = 1.0f / ls[qf];
    #pragma unroll
    for (int df=0;df<4;++df){
      ushort4 o4;
      o4.x = f2bf(acc[qf][df][0]*inv);
      o4.y = f2bf(acc[qf][df][1]*inv);
      o4.z = f2bf(acc[qf][df][2]*inv);
      o4.w = f2bf(acc[qf][df][3]*inv);
      *(ushort4*)(Cc + (size_t)(b*NN + q0 + qf*16 + lr)*EE + h*DD + df*16 + lg*4) = o4;
    }
  }
}

// ---------------- output projection ----------------
__global__ __launch_bounds__(256) void gemm_o_k(const u16* __restrict__ Cc, const u16* __restrict__ Wot,
                                                float* __restrict__ out){
  const int rt = blockIdx.x;
  const int w = threadIdx.x >> 6, l = threadIdx.x & 63, lr = l & 15, lg = l >> 4;
  const int row0 = rt*64 + w*16;
  f32x4 acc[4];
  #pragma unroll
  for (int n=0;n<4;++n) acc[n] = f32x4{0.f,0.f,0.f,0.f};

  for (int kt=0; kt<12; ++kt){
    const int e0 = kt*64;
    bf16x8 a[2], bb[4][2];
    #pragma unroll
    for (int ks=0;ks<2;++ks)
      a[ks] = ld8(Cc + (size_t)(row0 + lr)*EE + e0 + ks*32 + lg*8);
    #pragma unroll
    for (int nf=0;nf<4;++nf)
      #pragma unroll
      for (int ks=0;ks<2;++ks)
        bb[nf][ks] = ld8(Wot + (size_t)(nf*16 + lr)*EE + e0 + ks*32 + lg*8);
    #pragma unroll
    for (int ks=0;ks<2;++ks)
      #pragma unroll
      for (int nf=0;nf<4;++nf)
        acc[nf] = mfma16(a[ks], bb[nf][ks], acc[nf]);
  }
  #pragma unroll
  for (int nf=0;nf<4;++nf)
    #pragma unroll
    for (int j=0;j<4;++j)
      out[(size_t)(row0 + lg*4 + j)*DD + nf*16 + lr] = acc[nf][j];
}

// ---------------- launch ----------------
extern "C" void kernel_launch(void* const* d_in, const int* in_sizes, int n_in,
                              void* d_out, int out_size, void* d_ws, size_t ws_size,
                              hipStream_t stream) {
  const float* x  = (const float*)d_in[0];
  const float* Wq = (const float*)d_in[1];
  const float* Wk = (const float*)d_in[2];
  const float* Wv = (const float*)d_in[3];
  const float* Wo = (const float*)d_in[4];
  float* out = (float*)d_out;

  u16* ws = (u16*)d_ws;
  const size_t SB = (size_t)12582912;   // 16384*768
  u16* Xh  = ws;
  u16* Xl  = Xh + SB;
  u16* Qh  = Xl + SB;
  u16* Ql  = Qh + SB;
  u16* Kh  = Ql + SB;
  u16* Kl  = Kh + SB;
  u16* Vt  = Kl + SB;
  u16* Cc  = Vt + SB;
  u16* Wot = Cc + SB;
  // BT1/BT2 alias into Cc: written by packs, read by GEMMs, then Cc is fully
  // overwritten by flash_k before gemm_o_k reads it (in-stream ordering).
  u16* BT1 = Cc;                        // 1536*2304 = 3538944 elems
  u16* BT2 = Cc + 3538944;              // 768*768   =  589824 elems

  split_x_k <<<12288, 256, 0, stream>>>(x, Xh, Xl);
  pack_bt1_k<<<13824, 256, 0, stream>>>(Wq, Wk, BT1);
  pack_bt2_k<<<2304,  256, 0, stream>>>(Wv, BT2);
  pack_wo_k <<<192,   256, 0, stream>>>(Wo, Wot);

  gemm_big_k<36,0><<<1536, 256, 0, stream>>>(Xh, Xl, BT1, Qh, Ql, Kh, Kl);
  gemm_big_k<12,1><<<768,  256, 0, stream>>>(Xh, Xl, BT2, Vt, nullptr, nullptr, nullptr);
  flash_k   <<<1536, 256, 0, stream>>>(Qh, Ql, Kh, Kl, Vt, Cc);
  gemm_o_k  <<<256,  256, 0, stream>>>(Cc, Wot, out);
}